// Round 10
// baseline (204.634 us; speedup 1.0000x reference)
//
#include <hip/hip_runtime.h>

// VSGNet fused pipeline — fp32 in/out, bf16 MFMA compute.
// B=64 P=16 L=16 D=1024 SP=32 PROJ=512 ACT=29, C=16384.
// R9 post-mortem: fused_gemms 50us at MfmaUtil 4.7% — math takes 5% of kernel
// lifetime, rest is latency. R10: re-partition launches by TRUE dependencies:
// prep -> gemm3s (split-K=2, f32 atomics, 528 blocks) -> combo{mega+relu+bt32}
// (1136 blocks — relu/bt32 are independent of mega and soak its latency) ->
// pgraph. Wave-level co-scheduling (MFMA/VALU pipes separate) hides the
// relu/bt32 cost under mega.

typedef unsigned short u16;   // bf16 bits
typedef short s16x8 __attribute__((ext_vector_type(8)));
typedef float f32x4 __attribute__((ext_vector_type(4)));

__device__ __forceinline__ u16 f2b(float f) {
    union { float f; unsigned int i; } v; v.f = f;
    unsigned int r = (v.i + 0x7fffu + ((v.i >> 16) & 1u)) >> 16;  // RNE
    return (u16)r;
}
__device__ __forceinline__ float b2f(u16 u) {
    union { float f; unsigned int i; } v; v.i = ((unsigned int)u) << 16; return v.f;
}
__device__ __forceinline__ unsigned int pack2(float x, float y) {
    return (unsigned int)f2b(x) | ((unsigned int)f2b(y) << 16);
}

// ---------------- workspace layout (bytes) ----------------
#define OFF_WSPATT 0u         // [512][32]  bf16
#define OFF_WREFT  32768u     // [32][512]  bf16 (rows 29..31 zero)
#define OFF_WATTT  65536u     // [32][512]  bf16
#define OFF_WGT    98304u     // [32][2048] bf16
#define OFF_ADJ    2392064u   // [16384] f32
#define OFF_HP     2457600u   // [1024][32] f32
#define OFF_HOF    2588672u   // [1024][32] f32
#define OFF_YH     2719744u   // [1024][32] f32
#define OFF_ZO     2850816u   // [960][32]  f32
#define ZERO_OFF   2457600u
#define ZERO_LEN   516096u
#define OFF_WVIST2 2973696u   // [512][3072] bf16 (n-major, k contiguous)
#define OFF_WHOT2  6119424u   // [1024][1024] bf16
#define OFF_WOHT2  8216576u   // [1024][1024] bf16
#define OFF_PEOB   10313728u  // [1024][1024] bf16
#define OFF_OBJB   12410880u  // [1024][1024] bf16
#define OFF_CTXB   14508032u  // [64][1024]  bf16
#define OFF_SPATB  14639104u  // [16384][32] bf16
#define OFF_PPF    15687680u  // [1024][512] f32 (atomic, split-K)
#define OFF_POF    17784832u  // [1024][512] f32
#define OFF_PCF    19881984u  // [64][512]  f32
#define ZERO2_OFF  15687680u
#define ZERO2_LEN  4325376u

// ---------------- prep: LDS-tiled big transposes + vectorized converts ------
__global__ __launch_bounds__(256) void prep_all(
    const float* __restrict__ people, const float* __restrict__ objects,
    const float* __restrict__ context, const float* __restrict__ spatial,
    const float* __restrict__ Wvis, const float* __restrict__ Who,
    const float* __restrict__ Woh, const float* __restrict__ Wspat,
    const float* __restrict__ Wref, const float* __restrict__ Watt,
    const float* __restrict__ Wg,
    u16* __restrict__ peoB, u16* __restrict__ objB, u16* __restrict__ ctxB,
    u16* __restrict__ spatB, u16* __restrict__ WvisT, u16* __restrict__ WhoT,
    u16* __restrict__ WohT, u16* __restrict__ WspatT, u16* __restrict__ WrefT,
    u16* __restrict__ WattT, u16* __restrict__ WgT)
{
    __shared__ float S[64][65];
    int bid = blockIdx.x, t = threadIdx.x;
    if (bid < 896) {
        const float* src; u16* dst; int N, K, kt, nt;
        int tb = bid;
        if (tb < 256)      { src = Who;  dst = WhoT;  K = 1024; N = 1024; kt = tb >> 4; nt = tb & 15; }
        else if (tb < 512) { tb -= 256; src = Woh;  dst = WohT;  K = 1024; N = 1024; kt = tb >> 4; nt = tb & 15; }
        else               { tb -= 512; src = Wvis; dst = WvisT; K = 3072; N = 512;  kt = tb >> 3; nt = tb & 7; }
        int k0 = kt * 64, n0 = nt * 64;
        int tx = t & 63, ty = t >> 6;
#pragma unroll
        for (int i = 0; i < 16; i++)
            S[ty + 4 * i][tx] = src[(size_t)(k0 + ty + 4 * i) * N + n0 + tx];
        __syncthreads();
#pragma unroll
        for (int i = 0; i < 16; i++)
            dst[(size_t)(n0 + ty + 4 * i) * K + k0 + tx] = f2b(S[tx][ty + 4 * i]);
        return;
    }
    int g = (bid - 896) * 256 + t;
    const int gsz = 512 * 256;
    for (int i = g; i < 524288; i += gsz) {
        float2 v = ((const float2*)people)[i];
        ((unsigned int*)peoB)[i] = pack2(v.x, v.y);
    }
    for (int i = g; i < 524288; i += gsz) {
        float2 v = ((const float2*)objects)[i];
        ((unsigned int*)objB)[i] = pack2(v.x, v.y);
    }
    for (int i = g; i < 32768; i += gsz) {
        float2 v = ((const float2*)context)[i];
        ((unsigned int*)ctxB)[i] = pack2(v.x, v.y);
    }
    for (int i = g; i < 262144; i += gsz) {
        float2 v = ((const float2*)spatial)[i];
        ((unsigned int*)spatB)[i] = pack2(v.x, v.y);
    }
    for (int i = g; i < 512 * 32; i += gsz) {
        int n = i >> 5, k = i & 31;
        WspatT[i] = f2b(Wspat[k * 512 + n]);
    }
    for (int i = g; i < 32 * 512; i += gsz) {
        int n = i >> 9, k = i & 511;
        WrefT[i] = (n < 29) ? f2b(Wref[k * 29 + n]) : (u16)0;
        WattT[i] = (n < 29) ? f2b(Watt[k * 29 + n]) : (u16)0;
    }
    for (int i = g; i < 32 * 2048; i += gsz) {
        int n = i >> 11, k = i & 2047;
        WgT[i] = (n < 29) ? f2b(Wg[k * 29 + n]) : (u16)0;
    }
}

// ---- gemm3s: {PpF,PoF,PcF} += {peoB,objB,ctxB} @ WvisT slice, split-K=2 ----
// grid (8, 33, 2); 64x64 tile, depth-2 pipeline, 16 k-iters, f32 atomicAdd out.
__global__ __launch_bounds__(256) void gemm3s(
    const u16* __restrict__ peoB, const u16* __restrict__ objB,
    const u16* __restrict__ ctxB, const u16* __restrict__ WvisT,
    float* __restrict__ PpF, float* __restrict__ PoF, float* __restrict__ PcF)
{
    int t = threadIdx.x;
    int lane = t & 63, w = t >> 6;
    int l16 = lane & 15, q = lane >> 4;
    int wy = w >> 1, wx = w & 1;
    int ty = blockIdx.y;
    const u16* A; float* outF; int koff, bm;
    if (ty < 16)      { A = peoB; outF = PpF; koff = 0;    bm = ty * 64; }
    else if (ty < 32) { A = objB; outF = PoF; koff = 1024; bm = (ty - 16) * 64; }
    else              { A = ctxB; outF = PcF; bm = 0; koff = 2048; }
    int bn = blockIdx.x * 64;
    int k0 = blockIdx.z * 512;

    const u16* ap0 = A + (size_t)(bm + wy * 32 + l16) * 1024 + k0 + q * 8;
    const u16* ap1 = ap0 + (size_t)16 * 1024;
    const u16* bp0 = WvisT + (size_t)(bn + wx * 32 + l16) * 3072 + koff + k0 + q * 8;
    const u16* bp1 = bp0 + (size_t)16 * 3072;

    f32x4 acc00 = {0,0,0,0}, acc01 = {0,0,0,0}, acc10 = {0,0,0,0}, acc11 = {0,0,0,0};
    s16x8 ca0 = *(const s16x8*)ap0,        ca1 = *(const s16x8*)ap1;
    s16x8 cb0 = *(const s16x8*)bp0,        cb1 = *(const s16x8*)bp1;
    s16x8 na0 = *(const s16x8*)(ap0 + 32), na1 = *(const s16x8*)(ap1 + 32);
    s16x8 nb0 = *(const s16x8*)(bp0 + 32), nb1 = *(const s16x8*)(bp1 + 32);
    ap0 += 64; ap1 += 64; bp0 += 64; bp1 += 64;
    for (int it = 0; it < 14; it++) {
        s16x8 ta0 = *(const s16x8*)ap0, ta1 = *(const s16x8*)ap1;
        s16x8 tb0 = *(const s16x8*)bp0, tb1 = *(const s16x8*)bp1;
        ap0 += 32; ap1 += 32; bp0 += 32; bp1 += 32;
        acc00 = __builtin_amdgcn_mfma_f32_16x16x32_bf16(ca0, cb0, acc00, 0, 0, 0);
        acc01 = __builtin_amdgcn_mfma_f32_16x16x32_bf16(ca0, cb1, acc01, 0, 0, 0);
        acc10 = __builtin_amdgcn_mfma_f32_16x16x32_bf16(ca1, cb0, acc10, 0, 0, 0);
        acc11 = __builtin_amdgcn_mfma_f32_16x16x32_bf16(ca1, cb1, acc11, 0, 0, 0);
        ca0 = na0; ca1 = na1; cb0 = nb0; cb1 = nb1;
        na0 = ta0; na1 = ta1; nb0 = tb0; nb1 = tb1;
    }
    acc00 = __builtin_amdgcn_mfma_f32_16x16x32_bf16(ca0, cb0, acc00, 0, 0, 0);
    acc01 = __builtin_amdgcn_mfma_f32_16x16x32_bf16(ca0, cb1, acc01, 0, 0, 0);
    acc10 = __builtin_amdgcn_mfma_f32_16x16x32_bf16(ca1, cb0, acc10, 0, 0, 0);
    acc11 = __builtin_amdgcn_mfma_f32_16x16x32_bf16(ca1, cb1, acc11, 0, 0, 0);
    acc00 = __builtin_amdgcn_mfma_f32_16x16x32_bf16(na0, nb0, acc00, 0, 0, 0);
    acc01 = __builtin_amdgcn_mfma_f32_16x16x32_bf16(na0, nb1, acc01, 0, 0, 0);
    acc10 = __builtin_amdgcn_mfma_f32_16x16x32_bf16(na1, nb0, acc10, 0, 0, 0);
    acc11 = __builtin_amdgcn_mfma_f32_16x16x32_bf16(na1, nb1, acc11, 0, 0, 0);

    f32x4 accs[2][2] = {{acc00, acc01}, {acc10, acc11}};
#pragma unroll
    for (int ii = 0; ii < 2; ii++)
#pragma unroll
        for (int jj = 0; jj < 2; jj++) {
            int col = bn + wx * 32 + jj * 16 + l16;
#pragma unroll
            for (int r = 0; r < 4; r++) {
                int row = bm + wy * 32 + ii * 16 + q * 4 + r;
                atomicAdd(&outF[(size_t)row * 512 + col], accs[ii][jj][r]);
            }
        }
}

// ---------------- combo: mega(512) + relu(496) + bt32(128) = 1136 blocks ----
__global__ __launch_bounds__(256) void combo(
    const u16* __restrict__ spatB, const u16* __restrict__ WspatT,
    const float* __restrict__ bspat,
    const float* __restrict__ PpF, const float* __restrict__ PoF,
    const float* __restrict__ PcF, const float* __restrict__ bvis,
    const u16* __restrict__ WrefT, const float* __restrict__ bref,
    const u16* __restrict__ WattT, const float* __restrict__ batt,
    const float* __restrict__ wip, const float* __restrict__ bip,
    float* __restrict__ outI, float* __restrict__ outRef,
    float* __restrict__ outAtt, float* __restrict__ adjw,
    const u16* __restrict__ peoB, const u16* __restrict__ objB,
    const u16* __restrict__ WhoT, const float* __restrict__ Who_b,
    const u16* __restrict__ WohT, const float* __restrict__ Woh_b,
    const u16* __restrict__ WgT,
    float* __restrict__ Yh, float* __restrict__ Zo,
    float* __restrict__ Hp, float* __restrict__ HoF)
{
    __shared__ __align__(16) char smem[35840];
    int bid = blockIdx.x;
    int t = threadIdx.x;
    int lane = t & 63, w = t >> 6;
    int l16 = lane & 15, q = lane >> 4;
    int wy = w >> 1, wx = w & 1;

    if (bid < 512) {
        // ================= mega tile (32 rows of C) =================
        u16 (*tile)[512] = (u16(*)[512])smem;             // 32768
        float (*part)[8] = (float(*)[8])(smem + 32768);   // 1024
        float* wipS = (float*)(smem + 33792);             // 2048
        int c0 = bid * 32;
        {
            float2 u = *(const float2*)(wip + t * 2);
            wipS[t * 2]     = u.x;
            wipS[t * 2 + 1] = u.y;
        }
        // step 1: aho; wave w owns cols [w*128, w*128+128)
        {
            s16x8 a0 = *(const s16x8*)(spatB + (size_t)(c0 + l16) * 32 + q * 8);
            s16x8 a1 = *(const s16x8*)(spatB + (size_t)(c0 + 16 + l16) * 32 + q * 8);
            const u16* wb = WspatT + (size_t)(w * 128 + l16) * 32 + q * 8;
            s16x8 cb = *(const s16x8*)wb;
            s16x8 nb_ = *(const s16x8*)(wb + 16 * 32);
            wb += 32 * 32;
#pragma unroll
            for (int nt = 0; nt < 8; nt++) {
                s16x8 tb = nb_;
                if (nt < 6) { tb = *(const s16x8*)wb; wb += 16 * 32; }
                int n = w * 128 + nt * 16;
                f32x4 acc0 = {0,0,0,0}, acc1 = {0,0,0,0};
                acc0 = __builtin_amdgcn_mfma_f32_16x16x32_bf16(a0, cb, acc0, 0, 0, 0);
                acc1 = __builtin_amdgcn_mfma_f32_16x16x32_bf16(a1, cb, acc1, 0, 0, 0);
                cb = nb_; nb_ = tb;
                float bias = bspat[n + l16];
#pragma unroll
                for (int r = 0; r < 4; r++) {
                    tile[q * 4 + r][n + l16]      = f2b(fmaxf(acc0[r] + bias, 0.f));
                    tile[16 + q * 4 + r][n + l16] = f2b(fmaxf(acc1[r] + bias, 0.f));
                }
            }
        }
        __syncthreads();
        // step 2: p_att
        {
            int rt = w >> 1, ct = w & 1;
            const u16* bp = WattT + (size_t)(ct * 16 + l16) * 512 + q * 8;
            f32x4 acc = {0,0,0,0};
            s16x8 cb = *(const s16x8*)bp;
            s16x8 nb_ = *(const s16x8*)(bp + 32);
            bp += 64;
            for (int i = 0; i < 14; i++) {
                s16x8 tb = *(const s16x8*)bp; bp += 32;
                s16x8 a = *(const s16x8*)(&tile[rt * 16 + l16][i * 32 + q * 8]);
                acc = __builtin_amdgcn_mfma_f32_16x16x32_bf16(a, cb, acc, 0, 0, 0);
                cb = nb_; nb_ = tb;
            }
            {
                s16x8 a = *(const s16x8*)(&tile[rt * 16 + l16][14 * 32 + q * 8]);
                acc = __builtin_amdgcn_mfma_f32_16x16x32_bf16(a, cb, acc, 0, 0, 0);
                a = *(const s16x8*)(&tile[rt * 16 + l16][15 * 32 + q * 8]);
                acc = __builtin_amdgcn_mfma_f32_16x16x32_bf16(a, nb_, acc, 0, 0, 0);
            }
            int col = ct * 16 + l16;
            if (col < 29) {
                float bias = batt[col];
#pragma unroll
                for (int r = 0; r < 4; r++) {
                    int row = c0 + rt * 16 + q * 4 + r;
                    outAtt[(size_t)row * 29 + col] = acc[r] + bias;
                }
            }
        }
        __syncthreads();
        // step 3: fref in-place; i_ho partials (PpF/PoF/PcF are f32 now)
        {
            int row = t >> 3, g = t & 7;
            int c = c0 + row;
            int rp = c >> 4, bimg = c >> 8;
            int ro = bimg * 16 + (c & 15);
            const float* ppr = PpF + (size_t)rp * 512;
            const float* por = PoF + (size_t)ro * 512;
            const float* pcr = PcF + (size_t)bimg * 512;
            float ps = 0.f;
#pragma unroll 4
            for (int j = 0; j < 64; j += 2) {
                int col = g * 64 + j;
                float2 pp = *(const float2*)(ppr + col);
                float2 po = *(const float2*)(por + col);
                float2 pc = *(const float2*)(pcr + col);
                float2 bv = *(const float2*)(bvis + col);
                unsigned int uah = *(const unsigned int*)(&tile[row][col]);
                float fv0 = fmaxf(pp.x + po.x + pc.x + bv.x, 0.f);
                float fv1 = fmaxf(pp.y + po.y + pc.y + bv.y, 0.f);
                float fr0 = fv0 * b2f((u16)(uah & 0xffff));
                float fr1 = fv1 * b2f((u16)(uah >> 16));
                *(unsigned int*)(&tile[row][col]) = pack2(fr0, fr1);
                ps += fr0 * wipS[col] + fr1 * wipS[col + 1];
            }
            part[row][g] = ps;
        }
        __syncthreads();
        if (t < 32) {
            float s = part[t][0] + part[t][1] + part[t][2] + part[t][3]
                    + part[t][4] + part[t][5] + part[t][6] + part[t][7] + bip[0];
            outI[c0 + t] = s;
            adjw[c0 + t] = 1.f / (1.f + expf(-s));
        }
        // step 4: p_ref
        {
            int rt = w >> 1, ct = w & 1;
            const u16* bp = WrefT + (size_t)(ct * 16 + l16) * 512 + q * 8;
            f32x4 acc = {0,0,0,0};
            s16x8 cb = *(const s16x8*)bp;
            s16x8 nb_ = *(const s16x8*)(bp + 32);
            bp += 64;
            for (int i = 0; i < 14; i++) {
                s16x8 tb = *(const s16x8*)bp; bp += 32;
                s16x8 a = *(const s16x8*)(&tile[rt * 16 + l16][i * 32 + q * 8]);
                acc = __builtin_amdgcn_mfma_f32_16x16x32_bf16(a, cb, acc, 0, 0, 0);
                cb = nb_; nb_ = tb;
            }
            {
                s16x8 a = *(const s16x8*)(&tile[rt * 16 + l16][14 * 32 + q * 8]);
                acc = __builtin_amdgcn_mfma_f32_16x16x32_bf16(a, cb, acc, 0, 0, 0);
                a = *(const s16x8*)(&tile[rt * 16 + l16][15 * 32 + q * 8]);
                acc = __builtin_amdgcn_mfma_f32_16x16x32_bf16(a, nb_, acc, 0, 0, 0);
            }
            int col = ct * 16 + l16;
            if (col < 29) {
                float bias = bref[col];
#pragma unroll
                for (int r = 0; r < 4; r++) {
                    int row = c0 + rt * 16 + q * 4 + r;
                    outRef[(size_t)row * 29 + col] = acc[r] + bias;
                }
            }
        }
    } else if (bid < 1008) {
        // ================= relu-projection 64x64 =================
        u16 (*T)[72] = (u16(*)[72])smem;
        int r3 = bid - 512;
        int z, rt, nbt;
        if (r3 < 256) { z = 0; rt = r3 >> 4; nbt = r3 & 15; }
        else          { z = 1; r3 -= 256; rt = r3 >> 4; nbt = r3 & 15; }
        const u16* A    = z ? objB : peoB;
        const u16* W1T  = z ? WohT : WhoT;
        const float* bb = z ? Woh_b : Who_b;
        const u16* Wg2  = z ? WgT : WgT + 1024;
        float* U        = z ? Zo : Yh;
        int m0 = rt * 64, nb = nbt * 64;

        int r0 = m0 + wy * 32 + l16;
        int r1 = r0 + 16;
        if (z) { r0 = (r0 / 15) * 16 + (r0 % 15) + 1;
                 r1 = (r1 / 15) * 16 + (r1 % 15) + 1; }
        const u16* ap0 = A + (size_t)r0 * 1024 + q * 8;
        const u16* ap1 = A + (size_t)r1 * 1024 + q * 8;
        const u16* bp0 = W1T + (size_t)(nb + wx * 32 + l16) * 1024 + q * 8;
        const u16* bp1 = bp0 + (size_t)16 * 1024;

        f32x4 acc00 = {0,0,0,0}, acc01 = {0,0,0,0}, acc10 = {0,0,0,0}, acc11 = {0,0,0,0};
        s16x8 ca0 = *(const s16x8*)ap0,        ca1 = *(const s16x8*)ap1;
        s16x8 cb0 = *(const s16x8*)bp0,        cb1 = *(const s16x8*)bp1;
        s16x8 na0 = *(const s16x8*)(ap0 + 32), na1 = *(const s16x8*)(ap1 + 32);
        s16x8 nb0 = *(const s16x8*)(bp0 + 32), nb1 = *(const s16x8*)(bp1 + 32);
        ap0 += 64; ap1 += 64; bp0 += 64; bp1 += 64;
        for (int it = 0; it < 30; it++) {
            s16x8 ta0 = *(const s16x8*)ap0, ta1 = *(const s16x8*)ap1;
            s16x8 tb0 = *(const s16x8*)bp0, tb1 = *(const s16x8*)bp1;
            ap0 += 32; ap1 += 32; bp0 += 32; bp1 += 32;
            acc00 = __builtin_amdgcn_mfma_f32_16x16x32_bf16(ca0, cb0, acc00, 0, 0, 0);
            acc01 = __builtin_amdgcn_mfma_f32_16x16x32_bf16(ca0, cb1, acc01, 0, 0, 0);
            acc10 = __builtin_amdgcn_mfma_f32_16x16x32_bf16(ca1, cb0, acc10, 0, 0, 0);
            acc11 = __builtin_amdgcn_mfma_f32_16x16x32_bf16(ca1, cb1, acc11, 0, 0, 0);
            ca0 = na0; ca1 = na1; cb0 = nb0; cb1 = nb1;
            na0 = ta0; na1 = ta1; nb0 = tb0; nb1 = tb1;
        }
        acc00 = __builtin_amdgcn_mfma_f32_16x16x32_bf16(ca0, cb0, acc00, 0, 0, 0);
        acc01 = __builtin_amdgcn_mfma_f32_16x16x32_bf16(ca0, cb1, acc01, 0, 0, 0);
        acc10 = __builtin_amdgcn_mfma_f32_16x16x32_bf16(ca1, cb0, acc10, 0, 0, 0);
        acc11 = __builtin_amdgcn_mfma_f32_16x16x32_bf16(ca1, cb1, acc11, 0, 0, 0);
        acc00 = __builtin_amdgcn_mfma_f32_16x16x32_bf16(na0, nb0, acc00, 0, 0, 0);
        acc01 = __builtin_amdgcn_mfma_f32_16x16x32_bf16(na0, nb1, acc01, 0, 0, 0);
        acc10 = __builtin_amdgcn_mfma_f32_16x16x32_bf16(na1, nb0, acc10, 0, 0, 0);
        acc11 = __builtin_amdgcn_mfma_f32_16x16x32_bf16(na1, nb1, acc11, 0, 0, 0);

        f32x4 accs[2][2] = {{acc00, acc01}, {acc10, acc11}};
#pragma unroll
        for (int ii = 0; ii < 2; ii++)
#pragma unroll
            for (int jj = 0; jj < 2; jj++) {
                int col = wx * 32 + jj * 16 + l16;
                float bv = bb[nb + col];
#pragma unroll
                for (int rr = 0; rr < 4; rr++) {
                    float v = accs[ii][jj][rr] + bv;
                    T[wy * 32 + ii * 16 + q * 4 + rr][col] = f2b(fmaxf(v, 0.f));
                }
            }
        __syncthreads();

        f32x4 s20 = {0,0,0,0}, s21 = {0,0,0,0};
#pragma unroll
        for (int kk = 0; kk < 64; kk += 32) {
            s16x8 a2 = *(const s16x8*)(&T[w * 16 + l16][kk + q * 8]);
            s16x8 b20 = *(const s16x8*)(Wg2 + (size_t)l16 * 2048 + nb + kk + q * 8);
            s16x8 b21 = *(const s16x8*)(Wg2 + (size_t)(16 + l16) * 2048 + nb + kk + q * 8);
            s20 = __builtin_amdgcn_mfma_f32_16x16x32_bf16(a2, b20, s20, 0, 0, 0);
            s21 = __builtin_amdgcn_mfma_f32_16x16x32_bf16(a2, b21, s21, 0, 0, 0);
        }
#pragma unroll
        for (int rr = 0; rr < 4; rr++) {
            int row = m0 + w * 16 + q * 4 + rr;
            atomicAdd(&U[(size_t)row * 32 + l16], s20[rr]);
            atomicAdd(&U[(size_t)row * 32 + 16 + l16], s21[rr]);
        }
    } else {
        // ================= bt32 split-K =================
        int r3 = bid - 1008;
        int bx = r3 & 7, by = (r3 >> 3) & 7, z = r3 >> 6;
        const u16* A  = z ? objB : peoB;
        const u16* BT = z ? WgT + 1024 : WgT;
        float* outF   = z ? HoF : Hp;
        int bm = bx * 128 + w * 32;
        int kb = by * 128;
        const u16* ap0 = A + (size_t)(bm + l16) * 1024 + kb + q * 8;
        const u16* ap1 = A + (size_t)(bm + 16 + l16) * 1024 + kb + q * 8;
        const u16* bp0 = BT + (size_t)l16 * 2048 + kb + q * 8;
        const u16* bp1 = BT + (size_t)(16 + l16) * 2048 + kb + q * 8;
        f32x4 acc00 = {0,0,0,0}, acc01 = {0,0,0,0}, acc10 = {0,0,0,0}, acc11 = {0,0,0,0};
        s16x8 ca0 = *(const s16x8*)ap0,        ca1 = *(const s16x8*)ap1;
        s16x8 cb0 = *(const s16x8*)bp0,        cb1 = *(const s16x8*)bp1;
        s16x8 na0 = *(const s16x8*)(ap0 + 32), na1 = *(const s16x8*)(ap1 + 32);
        s16x8 nb0 = *(const s16x8*)(bp0 + 32), nb1 = *(const s16x8*)(bp1 + 32);
        ap0 += 64; ap1 += 64; bp0 += 64; bp1 += 64;
#pragma unroll
        for (int it = 0; it < 2; it++) {
            s16x8 ta0 = *(const s16x8*)ap0, ta1 = *(const s16x8*)ap1;
            s16x8 tb0 = *(const s16x8*)bp0, tb1 = *(const s16x8*)bp1;
            ap0 += 32; ap1 += 32; bp0 += 32; bp1 += 32;
            acc00 = __builtin_amdgcn_mfma_f32_16x16x32_bf16(ca0, cb0, acc00, 0, 0, 0);
            acc01 = __builtin_amdgcn_mfma_f32_16x16x32_bf16(ca0, cb1, acc01, 0, 0, 0);
            acc10 = __builtin_amdgcn_mfma_f32_16x16x32_bf16(ca1, cb0, acc10, 0, 0, 0);
            acc11 = __builtin_amdgcn_mfma_f32_16x16x32_bf16(ca1, cb1, acc11, 0, 0, 0);
            ca0 = na0; ca1 = na1; cb0 = nb0; cb1 = nb1;
            na0 = ta0; na1 = ta1; nb0 = tb0; nb1 = tb1;
        }
        acc00 = __builtin_amdgcn_mfma_f32_16x16x32_bf16(ca0, cb0, acc00, 0, 0, 0);
        acc01 = __builtin_amdgcn_mfma_f32_16x16x32_bf16(ca0, cb1, acc01, 0, 0, 0);
        acc10 = __builtin_amdgcn_mfma_f32_16x16x32_bf16(ca1, cb0, acc10, 0, 0, 0);
        acc11 = __builtin_amdgcn_mfma_f32_16x16x32_bf16(ca1, cb1, acc11, 0, 0, 0);
        acc00 = __builtin_amdgcn_mfma_f32_16x16x32_bf16(na0, nb0, acc00, 0, 0, 0);
        acc01 = __builtin_amdgcn_mfma_f32_16x16x32_bf16(na0, nb1, acc01, 0, 0, 0);
        acc10 = __builtin_amdgcn_mfma_f32_16x16x32_bf16(na1, nb0, acc10, 0, 0, 0);
        acc11 = __builtin_amdgcn_mfma_f32_16x16x32_bf16(na1, nb1, acc11, 0, 0, 0);
        f32x4 accs[2][2] = {{acc00, acc01}, {acc10, acc11}};
#pragma unroll
        for (int ii = 0; ii < 2; ii++)
#pragma unroll
            for (int jj = 0; jj < 2; jj++)
#pragma unroll
                for (int r = 0; r < 4; r++)
                    atomicAdd(&outF[(size_t)(bm + ii * 16 + q * 4 + r) * 32 + jj * 16 + l16],
                              accs[ii][jj][r]);
    }
}

// ---- p_graph: per image, tiny adj contractions + broadcast sum -------------
__global__ __launch_bounds__(256) void pgraph2(
    const float* __restrict__ adjw, const float* __restrict__ Hp,
    const float* __restrict__ HoF, const float* __restrict__ Yh,
    const float* __restrict__ Zo, const float* __restrict__ bg,
    float* __restrict__ outG)
{
    int b = blockIdx.x, t = threadIdx.x;
    __shared__ float adjS[16][16];
    __shared__ float YhS[16][32];
    __shared__ float ZoS[15][32];
    __shared__ float PA[16][32];
    __shared__ float OA[16][32];
    adjS[t >> 4][t & 15] = adjw[b * 256 + t];
    for (int i = t; i < 512; i += 256)
        YhS[i >> 5][i & 31] = Yh[(size_t)(b * 16 + (i >> 5)) * 32 + (i & 31)];
    for (int i = t; i < 480; i += 256)
        ZoS[i >> 5][i & 31] = Zo[(size_t)(b * 15 + (i >> 5)) * 32 + (i & 31)];
    __syncthreads();
    for (int i = t; i < 512; i += 256) {
        int p = i >> 5, j = i & 31;
        float s = 0.f;
#pragma unroll
        for (int o = 0; o < 15; o++) s += adjS[p][o + 1] * ZoS[o][j];
        PA[p][j] = s;
        float s2 = 0.f;
#pragma unroll
        for (int pp = 0; pp < 16; pp++) s2 += adjS[pp][p] * YhS[pp][j];
        OA[p][j] = s2;
    }
    __syncthreads();
    int p = t >> 4, l = t & 15;
    const float* hp = Hp + (size_t)(b * 16 + p) * 32;
    const float* ho = HoF + (size_t)(b * 16 + l) * 32;
    size_t c = (size_t)b * 256 + t;
    for (int j = 0; j < 29; j++) {
        float v = hp[j] + ho[j] + bg[j] + PA[p][j];
        if (l >= 1) v += OA[l][j];
        outG[c * 29 + j] = v;
    }
}

extern "C" void kernel_launch(void* const* d_in, const int* in_sizes, int n_in,
                              void* d_out, int out_size, void* d_ws, size_t ws_size,
                              hipStream_t stream)
{
    const float* people  = (const float*)d_in[0];
    const float* objects = (const float*)d_in[1];
    const float* context = (const float*)d_in[2];
    const float* spatial = (const float*)d_in[3];
    const float* Wvis_w  = (const float*)d_in[4];
    const float* Wvis_b  = (const float*)d_in[5];
    const float* Wspat_w = (const float*)d_in[6];
    const float* Wspat_b = (const float*)d_in[7];
    const float* Wip_w   = (const float*)d_in[8];
    const float* Wip_b   = (const float*)d_in[9];
    const float* Wref_w  = (const float*)d_in[10];
    const float* Wref_b  = (const float*)d_in[11];
    const float* Watt_w  = (const float*)d_in[12];
    const float* Watt_b  = (const float*)d_in[13];
    const float* Woh_w   = (const float*)d_in[14];
    const float* Woh_b   = (const float*)d_in[15];
    const float* Who_w   = (const float*)d_in[16];
    const float* Who_b   = (const float*)d_in[17];
    const float* Wg_w    = (const float*)d_in[18];
    const float* Wg_b    = (const float*)d_in[19];

    char* ws = (char*)d_ws;
    u16* WspatT = (u16*)(ws + OFF_WSPATT);
    u16* WrefT  = (u16*)(ws + OFF_WREFT);
    u16* WattT  = (u16*)(ws + OFF_WATTT);
    u16* WgT    = (u16*)(ws + OFF_WGT);
    float* adjw = (float*)(ws + OFF_ADJ);
    float* Hp   = (float*)(ws + OFF_HP);
    float* HoF  = (float*)(ws + OFF_HOF);
    float* Yh   = (float*)(ws + OFF_YH);
    float* Zo   = (float*)(ws + OFF_ZO);
    u16* WvisT2 = (u16*)(ws + OFF_WVIST2);
    u16* WhoT2  = (u16*)(ws + OFF_WHOT2);
    u16* WohT2  = (u16*)(ws + OFF_WOHT2);
    u16* peoB   = (u16*)(ws + OFF_PEOB);
    u16* objB   = (u16*)(ws + OFF_OBJB);
    u16* ctxB   = (u16*)(ws + OFF_CTXB);
    u16* spatB  = (u16*)(ws + OFF_SPATB);
    float* PpF  = (float*)(ws + OFF_PPF);
    float* PoF  = (float*)(ws + OFF_POF);
    float* PcF  = (float*)(ws + OFF_PCF);

    float* outI   = (float*)d_out;        // i_ho   [16384]
    float* outRef = outI + 16384;         // p_ref  [16384,29]
    float* outAtt = outI + 491520;        // p_att  [16384,29]
    float* outG   = outI + 966656;        // p_graph[16384,29]

    hipMemsetAsync(ws + ZERO_OFF, 0, ZERO_LEN, stream);
    hipMemsetAsync(ws + ZERO2_OFF, 0, ZERO2_LEN, stream);

    prep_all<<<1408, 256, 0, stream>>>(people, objects, context, spatial,
        Wvis_w, Who_w, Woh_w, Wspat_w, Wref_w, Watt_w, Wg_w,
        peoB, objB, ctxB, spatB, WvisT2, WhoT2, WohT2,
        WspatT, WrefT, WattT, WgT);

    gemm3s<<<dim3(8, 33, 2), 256, 0, stream>>>(peoB, objB, ctxB, WvisT2,
                                               PpF, PoF, PcF);

    combo<<<1136, 256, 0, stream>>>(spatB, WspatT, Wspat_b,
        PpF, PoF, PcF, Wvis_b, WrefT, Wref_b, WattT, Watt_b,
        Wip_w, Wip_b, outI, outRef, outAtt, adjw,
        peoB, objB, WhoT2, Who_b, WohT2, Woh_b, WgT,
        Yh, Zo, Hp, HoF);

    pgraph2<<<64, 256, 0, stream>>>(adjw, Hp, HoF, Yh, Zo, Wg_b, outG);
}

// Round 11
// 189.613 us; speedup vs baseline: 1.0792x; 1.0792x over previous
//
#include <hip/hip_runtime.h>

// VSGNet fused pipeline — fp32 in/out, bf16 MFMA compute.
// B=64 P=16 L=16 D=1024 SP=32 PROJ=512 ACT=29, C=16384.
// R10 post-mortem: combo regressed (mega's 36KB LDS capped relu TLP; mega tile
// had 16-way LDS bank conflicts, 4.4M cycles). R11: revert to R9 partition;
// relu retiled to per-wave 64x32 (8 MFMA / 6 loads); mega tile padded to
// [32][520] (row stride = 4 banks mod 32 -> conflict-free).

typedef unsigned short u16;   // bf16 bits
typedef short s16x8 __attribute__((ext_vector_type(8)));
typedef float f32x4 __attribute__((ext_vector_type(4)));

__device__ __forceinline__ u16 f2b(float f) {
    union { float f; unsigned int i; } v; v.f = f;
    unsigned int r = (v.i + 0x7fffu + ((v.i >> 16) & 1u)) >> 16;  // RNE
    return (u16)r;
}
__device__ __forceinline__ float b2f(u16 u) {
    union { float f; unsigned int i; } v; v.i = ((unsigned int)u) << 16; return v.f;
}
__device__ __forceinline__ unsigned int pack2(float x, float y) {
    return (unsigned int)f2b(x) | ((unsigned int)f2b(y) << 16);
}

// ---------------- workspace layout (bytes) ----------------
#define OFF_WSPATT 0u         // [512][32]  bf16
#define OFF_WREFT  32768u     // [32][512]  bf16 (rows 29..31 zero)
#define OFF_WATTT  65536u     // [32][512]  bf16
#define OFF_WGT    98304u     // [32][2048] bf16
#define OFF_PP     229376u    // [1024][512] bf16
#define OFF_PO     1277952u   // [1024][512] bf16
#define OFF_PC     2326528u   // [64][512]  bf16
#define OFF_ADJ    2392064u   // [16384] f32
#define OFF_HP     2457600u   // [1024][32] f32
#define OFF_HOF    2588672u   // [1024][32] f32
#define OFF_YH     2719744u   // [1024][32] f32
#define OFF_ZO     2850816u   // [960][32]  f32
#define ZERO_OFF   2457600u
#define ZERO_LEN   516096u
#define OFF_WVIST2 2973696u   // [512][3072] bf16 (n-major, k contiguous)
#define OFF_WHOT2  6119424u   // [1024][1024] bf16
#define OFF_WOHT2  8216576u   // [1024][1024] bf16
#define OFF_PEOB   10313728u  // [1024][1024] bf16
#define OFF_OBJB   12410880u  // [1024][1024] bf16
#define OFF_CTXB   14508032u  // [64][1024]  bf16
#define OFF_SPATB  14639104u  // [16384][32] bf16

// ---------------- prep: LDS-tiled big transposes + vectorized converts ------
__global__ __launch_bounds__(256) void prep_all(
    const float* __restrict__ people, const float* __restrict__ objects,
    const float* __restrict__ context, const float* __restrict__ spatial,
    const float* __restrict__ Wvis, const float* __restrict__ Who,
    const float* __restrict__ Woh, const float* __restrict__ Wspat,
    const float* __restrict__ Wref, const float* __restrict__ Watt,
    const float* __restrict__ Wg,
    u16* __restrict__ peoB, u16* __restrict__ objB, u16* __restrict__ ctxB,
    u16* __restrict__ spatB, u16* __restrict__ WvisT, u16* __restrict__ WhoT,
    u16* __restrict__ WohT, u16* __restrict__ WspatT, u16* __restrict__ WrefT,
    u16* __restrict__ WattT, u16* __restrict__ WgT)
{
    __shared__ float S[64][65];
    int bid = blockIdx.x, t = threadIdx.x;
    if (bid < 896) {
        const float* src; u16* dst; int N, K, kt, nt;
        int tb = bid;
        if (tb < 256)      { src = Who;  dst = WhoT;  K = 1024; N = 1024; kt = tb >> 4; nt = tb & 15; }
        else if (tb < 512) { tb -= 256; src = Woh;  dst = WohT;  K = 1024; N = 1024; kt = tb >> 4; nt = tb & 15; }
        else               { tb -= 512; src = Wvis; dst = WvisT; K = 3072; N = 512;  kt = tb >> 3; nt = tb & 7; }
        int k0 = kt * 64, n0 = nt * 64;
        int tx = t & 63, ty = t >> 6;
#pragma unroll
        for (int i = 0; i < 16; i++)
            S[ty + 4 * i][tx] = src[(size_t)(k0 + ty + 4 * i) * N + n0 + tx];
        __syncthreads();
#pragma unroll
        for (int i = 0; i < 16; i++)
            dst[(size_t)(n0 + ty + 4 * i) * K + k0 + tx] = f2b(S[tx][ty + 4 * i]);
        return;
    }
    int g = (bid - 896) * 256 + t;
    const int gsz = 512 * 256;
    for (int i = g; i < 524288; i += gsz) {
        float2 v = ((const float2*)people)[i];
        ((unsigned int*)peoB)[i] = pack2(v.x, v.y);
    }
    for (int i = g; i < 524288; i += gsz) {
        float2 v = ((const float2*)objects)[i];
        ((unsigned int*)objB)[i] = pack2(v.x, v.y);
    }
    for (int i = g; i < 32768; i += gsz) {
        float2 v = ((const float2*)context)[i];
        ((unsigned int*)ctxB)[i] = pack2(v.x, v.y);
    }
    for (int i = g; i < 262144; i += gsz) {
        float2 v = ((const float2*)spatial)[i];
        ((unsigned int*)spatB)[i] = pack2(v.x, v.y);
    }
    for (int i = g; i < 512 * 32; i += gsz) {
        int n = i >> 5, k = i & 31;
        WspatT[i] = f2b(Wspat[k * 512 + n]);
    }
    for (int i = g; i < 32 * 512; i += gsz) {
        int n = i >> 9, k = i & 511;
        WrefT[i] = (n < 29) ? f2b(Wref[k * 29 + n]) : (u16)0;
        WattT[i] = (n < 29) ? f2b(Watt[k * 29 + n]) : (u16)0;
    }
    for (int i = g; i < 32 * 2048; i += gsz) {
        int n = i >> 11, k = i & 2047;
        WgT[i] = (n < 29) ? f2b(Wg[k * 29 + n]) : (u16)0;
    }
}

// ---------------- fused post-prep GEMMs (flat 648-block grid) ---------------
// [0,264):   Pp/Po/Pc = {peoB,objB,ctxB} @ WvisT  (64x64, depth-2 pipeline)
// [264,520): Yh/Zo relu-projection, block 128x64, wave 64x32 (8 MFMA : 6 loads)
// [520,648): Hp/HoF split-K (atomicAdd)
__global__ __launch_bounds__(256) void fused_gemms(
    const u16* __restrict__ peoB, const u16* __restrict__ objB,
    const u16* __restrict__ ctxB, const u16* __restrict__ WvisT,
    const u16* __restrict__ WhoT, const float* __restrict__ Who_b,
    const u16* __restrict__ WohT, const float* __restrict__ Woh_b,
    const u16* __restrict__ WgT,
    u16* __restrict__ Pp, u16* __restrict__ Po, u16* __restrict__ Pc,
    float* __restrict__ Yh, float* __restrict__ Zo,
    float* __restrict__ Hp, float* __restrict__ HoF)
{
    __shared__ u16 T[128][72];
    int bid = blockIdx.x;
    int t = threadIdx.x;
    int lane = t & 63, w = t >> 6;
    int l16 = lane & 15, q = lane >> 4;
    int wy = w >> 1, wx = w & 1;

    if (bid < 264) {
        // ---------------- gemm3: 64x64 tile, K=1024 ----------------
        int bx = bid & 7, ty = bid >> 3;
        const u16* A; u16* outB; int koff, bm;
        if (ty < 16)      { A = peoB; outB = Pp; koff = 0;    bm = ty * 64; }
        else if (ty < 32) { A = objB; outB = Po; koff = 1024; bm = (ty - 16) * 64; }
        else              { A = ctxB; outB = Pc; koff = 2048; bm = 0; }
        int bn = bx * 64;

        const u16* ap0 = A + (size_t)(bm + wy * 32 + l16) * 1024 + q * 8;
        const u16* ap1 = ap0 + (size_t)16 * 1024;
        const u16* bp0 = WvisT + (size_t)(bn + wx * 32 + l16) * 3072 + koff + q * 8;
        const u16* bp1 = bp0 + (size_t)16 * 3072;

        f32x4 acc00 = {0,0,0,0}, acc01 = {0,0,0,0}, acc10 = {0,0,0,0}, acc11 = {0,0,0,0};
        s16x8 ca0 = *(const s16x8*)ap0,        ca1 = *(const s16x8*)ap1;
        s16x8 cb0 = *(const s16x8*)bp0,        cb1 = *(const s16x8*)bp1;
        s16x8 na0 = *(const s16x8*)(ap0 + 32), na1 = *(const s16x8*)(ap1 + 32);
        s16x8 nb0 = *(const s16x8*)(bp0 + 32), nb1 = *(const s16x8*)(bp1 + 32);
        ap0 += 64; ap1 += 64; bp0 += 64; bp1 += 64;
        for (int it = 0; it < 30; it++) {
            s16x8 ta0 = *(const s16x8*)ap0, ta1 = *(const s16x8*)ap1;
            s16x8 tb0 = *(const s16x8*)bp0, tb1 = *(const s16x8*)bp1;
            ap0 += 32; ap1 += 32; bp0 += 32; bp1 += 32;
            acc00 = __builtin_amdgcn_mfma_f32_16x16x32_bf16(ca0, cb0, acc00, 0, 0, 0);
            acc01 = __builtin_amdgcn_mfma_f32_16x16x32_bf16(ca0, cb1, acc01, 0, 0, 0);
            acc10 = __builtin_amdgcn_mfma_f32_16x16x32_bf16(ca1, cb0, acc10, 0, 0, 0);
            acc11 = __builtin_amdgcn_mfma_f32_16x16x32_bf16(ca1, cb1, acc11, 0, 0, 0);
            ca0 = na0; ca1 = na1; cb0 = nb0; cb1 = nb1;
            na0 = ta0; na1 = ta1; nb0 = tb0; nb1 = tb1;
        }
        acc00 = __builtin_amdgcn_mfma_f32_16x16x32_bf16(ca0, cb0, acc00, 0, 0, 0);
        acc01 = __builtin_amdgcn_mfma_f32_16x16x32_bf16(ca0, cb1, acc01, 0, 0, 0);
        acc10 = __builtin_amdgcn_mfma_f32_16x16x32_bf16(ca1, cb0, acc10, 0, 0, 0);
        acc11 = __builtin_amdgcn_mfma_f32_16x16x32_bf16(ca1, cb1, acc11, 0, 0, 0);
        acc00 = __builtin_amdgcn_mfma_f32_16x16x32_bf16(na0, nb0, acc00, 0, 0, 0);
        acc01 = __builtin_amdgcn_mfma_f32_16x16x32_bf16(na0, nb1, acc01, 0, 0, 0);
        acc10 = __builtin_amdgcn_mfma_f32_16x16x32_bf16(na1, nb0, acc10, 0, 0, 0);
        acc11 = __builtin_amdgcn_mfma_f32_16x16x32_bf16(na1, nb1, acc11, 0, 0, 0);

        f32x4 accs[2][2] = {{acc00, acc01}, {acc10, acc11}};
#pragma unroll
        for (int ii = 0; ii < 2; ii++)
#pragma unroll
            for (int jj = 0; jj < 2; jj++) {
                int col = bn + wx * 32 + jj * 16 + l16;
#pragma unroll
                for (int r = 0; r < 4; r++) {
                    int row = bm + wy * 32 + ii * 16 + q * 4 + r;
                    outB[(size_t)row * 512 + col] = f2b(accs[ii][jj][r]);
                }
            }
    } else if (bid < 520) {
        // ------- relu-projection: block 128 rows x 64 cols, wave 64x32 -------
        int r3 = bid - 264;
        int z = r3 >> 7; r3 &= 127;
        int rt = r3 >> 4, nbt = r3 & 15;
        const u16* A    = z ? objB : peoB;
        const u16* W1T  = z ? WohT : WhoT;
        const float* bb = z ? Woh_b : Who_b;
        const u16* Wg2  = z ? WgT : WgT + 1024;
        float* U        = z ? Zo : Yh;
        int m0 = rt * 128, nb = nbt * 64;

        const u16* ap[4];
        int rb = m0 + wy * 64;
#pragma unroll
        for (int i = 0; i < 4; i++) {
            int rr = rb + i * 16 + l16;
            if (z) { int rc = rr < 960 ? rr : 959; rr = (rc / 15) * 16 + (rc % 15) + 1; }
            ap[i] = A + (size_t)rr * 1024 + q * 8;
        }
        const u16* bp0 = W1T + (size_t)(nb + wx * 32 + l16) * 1024 + q * 8;
        const u16* bp1 = bp0 + (size_t)16 * 1024;

        f32x4 acc[4][2] = {};
        s16x8 ca[4], na[4];
#pragma unroll
        for (int i = 0; i < 4; i++) {
            ca[i] = *(const s16x8*)ap[i];
            na[i] = *(const s16x8*)(ap[i] + 32);
            ap[i] += 64;
        }
        s16x8 cb0 = *(const s16x8*)bp0, nb0 = *(const s16x8*)(bp0 + 32);
        s16x8 cb1 = *(const s16x8*)bp1, nb1 = *(const s16x8*)(bp1 + 32);
        bp0 += 64; bp1 += 64;
        for (int it = 0; it < 30; it++) {
            s16x8 ta[4], tb0, tb1;
#pragma unroll
            for (int i = 0; i < 4; i++) { ta[i] = *(const s16x8*)ap[i]; ap[i] += 32; }
            tb0 = *(const s16x8*)bp0; bp0 += 32;
            tb1 = *(const s16x8*)bp1; bp1 += 32;
#pragma unroll
            for (int i = 0; i < 4; i++) {
                acc[i][0] = __builtin_amdgcn_mfma_f32_16x16x32_bf16(ca[i], cb0, acc[i][0], 0, 0, 0);
                acc[i][1] = __builtin_amdgcn_mfma_f32_16x16x32_bf16(ca[i], cb1, acc[i][1], 0, 0, 0);
            }
#pragma unroll
            for (int i = 0; i < 4; i++) { ca[i] = na[i]; na[i] = ta[i]; }
            cb0 = nb0; nb0 = tb0; cb1 = nb1; nb1 = tb1;
        }
#pragma unroll
        for (int i = 0; i < 4; i++) {
            acc[i][0] = __builtin_amdgcn_mfma_f32_16x16x32_bf16(ca[i], cb0, acc[i][0], 0, 0, 0);
            acc[i][1] = __builtin_amdgcn_mfma_f32_16x16x32_bf16(ca[i], cb1, acc[i][1], 0, 0, 0);
        }
#pragma unroll
        for (int i = 0; i < 4; i++) {
            acc[i][0] = __builtin_amdgcn_mfma_f32_16x16x32_bf16(na[i], nb0, acc[i][0], 0, 0, 0);
            acc[i][1] = __builtin_amdgcn_mfma_f32_16x16x32_bf16(na[i], nb1, acc[i][1], 0, 0, 0);
        }

        // bias + relu -> T[128][72]
#pragma unroll
        for (int i = 0; i < 4; i++)
#pragma unroll
            for (int j = 0; j < 2; j++) {
                int col = wx * 32 + j * 16 + l16;
                float bv = bb[nb + col];
#pragma unroll
                for (int r = 0; r < 4; r++) {
                    float v = acc[i][j][r] + bv;
                    T[wy * 64 + i * 16 + q * 4 + r][col] = f2b(fmaxf(v, 0.f));
                }
            }
        __syncthreads();

        // stage 2: U_part[128x32] = T(128x64) @ Wg2[nb:nb+64, :32]; wave 32 rows
        f32x4 s2[2][2] = {};
#pragma unroll
        for (int kk = 0; kk < 64; kk += 32) {
            s16x8 b20 = *(const s16x8*)(Wg2 + (size_t)l16 * 2048 + nb + kk + q * 8);
            s16x8 b21 = *(const s16x8*)(Wg2 + (size_t)(16 + l16) * 2048 + nb + kk + q * 8);
#pragma unroll
            for (int f = 0; f < 2; f++) {
                s16x8 a2 = *(const s16x8*)(&T[w * 32 + f * 16 + l16][kk + q * 8]);
                s2[f][0] = __builtin_amdgcn_mfma_f32_16x16x32_bf16(a2, b20, s2[f][0], 0, 0, 0);
                s2[f][1] = __builtin_amdgcn_mfma_f32_16x16x32_bf16(a2, b21, s2[f][1], 0, 0, 0);
            }
        }
#pragma unroll
        for (int f = 0; f < 2; f++)
#pragma unroll
            for (int r = 0; r < 4; r++) {
                int row = m0 + w * 32 + f * 16 + q * 4 + r;
                if (!z || row < 960) {
                    atomicAdd(&U[(size_t)row * 32 + l16], s2[f][0][r]);
                    atomicAdd(&U[(size_t)row * 32 + 16 + l16], s2[f][1][r]);
                }
            }
    } else {
        // ---------------- bt32 split-K: 128 rows, 128-k chunk ----------------
        int r3 = bid - 520;
        int bx = r3 & 7, by = (r3 >> 3) & 7, z = r3 >> 6;
        const u16* A  = z ? objB : peoB;
        const u16* BT = z ? WgT + 1024 : WgT;
        float* outF   = z ? HoF : Hp;
        int bm = bx * 128 + w * 32;
        int kb = by * 128;
        const u16* ap0 = A + (size_t)(bm + l16) * 1024 + kb + q * 8;
        const u16* ap1 = A + (size_t)(bm + 16 + l16) * 1024 + kb + q * 8;
        const u16* bp0 = BT + (size_t)l16 * 2048 + kb + q * 8;
        const u16* bp1 = BT + (size_t)(16 + l16) * 2048 + kb + q * 8;
        f32x4 acc00 = {0,0,0,0}, acc01 = {0,0,0,0}, acc10 = {0,0,0,0}, acc11 = {0,0,0,0};
        s16x8 ca0 = *(const s16x8*)ap0,        ca1 = *(const s16x8*)ap1;
        s16x8 cb0 = *(const s16x8*)bp0,        cb1 = *(const s16x8*)bp1;
        s16x8 na0 = *(const s16x8*)(ap0 + 32), na1 = *(const s16x8*)(ap1 + 32);
        s16x8 nb0 = *(const s16x8*)(bp0 + 32), nb1 = *(const s16x8*)(bp1 + 32);
        ap0 += 64; ap1 += 64; bp0 += 64; bp1 += 64;
#pragma unroll
        for (int it = 0; it < 2; it++) {
            s16x8 ta0 = *(const s16x8*)ap0, ta1 = *(const s16x8*)ap1;
            s16x8 tb0 = *(const s16x8*)bp0, tb1 = *(const s16x8*)bp1;
            ap0 += 32; ap1 += 32; bp0 += 32; bp1 += 32;
            acc00 = __builtin_amdgcn_mfma_f32_16x16x32_bf16(ca0, cb0, acc00, 0, 0, 0);
            acc01 = __builtin_amdgcn_mfma_f32_16x16x32_bf16(ca0, cb1, acc01, 0, 0, 0);
            acc10 = __builtin_amdgcn_mfma_f32_16x16x32_bf16(ca1, cb0, acc10, 0, 0, 0);
            acc11 = __builtin_amdgcn_mfma_f32_16x16x32_bf16(ca1, cb1, acc11, 0, 0, 0);
            ca0 = na0; ca1 = na1; cb0 = nb0; cb1 = nb1;
            na0 = ta0; na1 = ta1; nb0 = tb0; nb1 = tb1;
        }
        acc00 = __builtin_amdgcn_mfma_f32_16x16x32_bf16(ca0, cb0, acc00, 0, 0, 0);
        acc01 = __builtin_amdgcn_mfma_f32_16x16x32_bf16(ca0, cb1, acc01, 0, 0, 0);
        acc10 = __builtin_amdgcn_mfma_f32_16x16x32_bf16(ca1, cb0, acc10, 0, 0, 0);
        acc11 = __builtin_amdgcn_mfma_f32_16x16x32_bf16(ca1, cb1, acc11, 0, 0, 0);
        acc00 = __builtin_amdgcn_mfma_f32_16x16x32_bf16(na0, nb0, acc00, 0, 0, 0);
        acc01 = __builtin_amdgcn_mfma_f32_16x16x32_bf16(na0, nb1, acc01, 0, 0, 0);
        acc10 = __builtin_amdgcn_mfma_f32_16x16x32_bf16(na1, nb0, acc10, 0, 0, 0);
        acc11 = __builtin_amdgcn_mfma_f32_16x16x32_bf16(na1, nb1, acc11, 0, 0, 0);
        f32x4 accs[2][2] = {{acc00, acc01}, {acc10, acc11}};
#pragma unroll
        for (int ii = 0; ii < 2; ii++)
#pragma unroll
            for (int jj = 0; jj < 2; jj++)
#pragma unroll
                for (int r = 0; r < 4; r++)
                    atomicAdd(&outF[(size_t)(bm + ii * 16 + q * 4 + r) * 32 + jj * 16 + l16],
                              accs[ii][jj][r]);
    }
}

// ---- mega: per 32-row tile: aho(MFMA) -> p_att -> fref(in-place LDS)+i_ho -> p_ref
// tile padded to [32][520]: row stride 1040B = 260 dwords = 4 banks mod 32.
__global__ __launch_bounds__(256) void mega(
    const u16* __restrict__ spatB, const u16* __restrict__ WspatT,
    const float* __restrict__ bspat,
    const u16* __restrict__ Pp, const u16* __restrict__ Po,
    const u16* __restrict__ Pc, const float* __restrict__ bvis,
    const u16* __restrict__ WrefT, const float* __restrict__ bref,
    const u16* __restrict__ WattT, const float* __restrict__ batt,
    const float* __restrict__ wip, const float* __restrict__ bip,
    float* __restrict__ outI, float* __restrict__ outRef,
    float* __restrict__ outAtt, float* __restrict__ adjw)
{
    __shared__ u16 tile[32][520];
    __shared__ float part[32][8];
    __shared__ float wipS[512];
    int t = threadIdx.x;
    int c0 = blockIdx.x * 32;
    int lane = t & 63, w = t >> 6;
    int l16 = lane & 15, q = lane >> 4;

    {
        float2 u = *(const float2*)(wip + t * 2);
        wipS[t * 2]     = u.x;
        wipS[t * 2 + 1] = u.y;
    }

    // step 1: aho rows c0..c0+31; wave w owns cols [w*128, w*128+128)
    {
        s16x8 a0 = *(const s16x8*)(spatB + (size_t)(c0 + l16) * 32 + q * 8);
        s16x8 a1 = *(const s16x8*)(spatB + (size_t)(c0 + 16 + l16) * 32 + q * 8);
        const u16* wb = WspatT + (size_t)(w * 128 + l16) * 32 + q * 8;
        s16x8 cb = *(const s16x8*)wb;
        s16x8 nb_ = *(const s16x8*)(wb + 16 * 32);
        wb += 32 * 32;
#pragma unroll
        for (int nt = 0; nt < 8; nt++) {
            s16x8 tb = nb_;
            if (nt < 6) { tb = *(const s16x8*)wb; wb += 16 * 32; }
            int n = w * 128 + nt * 16;
            f32x4 acc0 = {0,0,0,0}, acc1 = {0,0,0,0};
            acc0 = __builtin_amdgcn_mfma_f32_16x16x32_bf16(a0, cb, acc0, 0, 0, 0);
            acc1 = __builtin_amdgcn_mfma_f32_16x16x32_bf16(a1, cb, acc1, 0, 0, 0);
            cb = nb_; nb_ = tb;
            float bias = bspat[n + l16];
#pragma unroll
            for (int r = 0; r < 4; r++) {
                tile[q * 4 + r][n + l16]      = f2b(fmaxf(acc0[r] + bias, 0.f));
                tile[16 + q * 4 + r][n + l16] = f2b(fmaxf(acc1[r] + bias, 0.f));
            }
        }
    }
    __syncthreads();

    // step 2: p_att = aho @ WattT^T + batt  (depth-2 on W loads)
    {
        int rt = w >> 1, ct = w & 1;
        const u16* bp = WattT + (size_t)(ct * 16 + l16) * 512 + q * 8;
        f32x4 acc = {0,0,0,0};
        s16x8 cb = *(const s16x8*)bp;
        s16x8 nb_ = *(const s16x8*)(bp + 32);
        bp += 64;
        for (int i = 0; i < 14; i++) {
            s16x8 tb = *(const s16x8*)bp; bp += 32;
            s16x8 a = *(const s16x8*)(&tile[rt * 16 + l16][i * 32 + q * 8]);
            acc = __builtin_amdgcn_mfma_f32_16x16x32_bf16(a, cb, acc, 0, 0, 0);
            cb = nb_; nb_ = tb;
        }
        {
            s16x8 a = *(const s16x8*)(&tile[rt * 16 + l16][14 * 32 + q * 8]);
            acc = __builtin_amdgcn_mfma_f32_16x16x32_bf16(a, cb, acc, 0, 0, 0);
            a = *(const s16x8*)(&tile[rt * 16 + l16][15 * 32 + q * 8]);
            acc = __builtin_amdgcn_mfma_f32_16x16x32_bf16(a, nb_, acc, 0, 0, 0);
        }
        int col = ct * 16 + l16;
        if (col < 29) {
            float bias = batt[col];
#pragma unroll
            for (int r = 0; r < 4; r++) {
                int row = c0 + rt * 16 + q * 4 + r;
                outAtt[(size_t)row * 29 + col] = acc[r] + bias;
            }
        }
    }
    __syncthreads();

    // step 3: fref = relu(Pp+Po+Pc+bvis) * aho (in-place); i_ho partials
    {
        int row = t >> 3, g = t & 7;
        int c = c0 + row;
        int rp = c >> 4, bimg = c >> 8;
        int ro = bimg * 16 + (c & 15);
        const u16* ppr = Pp + (size_t)rp * 512;
        const u16* por = Po + (size_t)ro * 512;
        const u16* pcr = Pc + (size_t)bimg * 512;
        float ps = 0.f;
#pragma unroll 4
        for (int j = 0; j < 64; j += 2) {
            int col = g * 64 + j;
            unsigned int upp = *(const unsigned int*)(ppr + col);
            unsigned int upo = *(const unsigned int*)(por + col);
            unsigned int upc = *(const unsigned int*)(pcr + col);
            float2 bv = *(const float2*)(bvis + col);
            unsigned int uah = *(const unsigned int*)(&tile[row][col]);
            float fv0 = fmaxf(b2f((u16)(upp & 0xffff)) + b2f((u16)(upo & 0xffff))
                            + b2f((u16)(upc & 0xffff)) + bv.x, 0.f);
            float fv1 = fmaxf(b2f((u16)(upp >> 16)) + b2f((u16)(upo >> 16))
                            + b2f((u16)(upc >> 16)) + bv.y, 0.f);
            float fr0 = fv0 * b2f((u16)(uah & 0xffff));
            float fr1 = fv1 * b2f((u16)(uah >> 16));
            *(unsigned int*)(&tile[row][col]) = pack2(fr0, fr1);
            ps += fr0 * wipS[col] + fr1 * wipS[col + 1];
        }
        part[row][g] = ps;
    }
    __syncthreads();

    if (t < 32) {
        float s = part[t][0] + part[t][1] + part[t][2] + part[t][3]
                + part[t][4] + part[t][5] + part[t][6] + part[t][7] + bip[0];
        outI[c0 + t] = s;
        adjw[c0 + t] = 1.f / (1.f + expf(-s));
    }

    // step 4: p_ref = fref @ WrefT^T + bref  (depth-2 on W loads)
    {
        int rt = w >> 1, ct = w & 1;
        const u16* bp = WrefT + (size_t)(ct * 16 + l16) * 512 + q * 8;
        f32x4 acc = {0,0,0,0};
        s16x8 cb = *(const s16x8*)bp;
        s16x8 nb_ = *(const s16x8*)(bp + 32);
        bp += 64;
        for (int i = 0; i < 14; i++) {
            s16x8 tb = *(const s16x8*)bp; bp += 32;
            s16x8 a = *(const s16x8*)(&tile[rt * 16 + l16][i * 32 + q * 8]);
            acc = __builtin_amdgcn_mfma_f32_16x16x32_bf16(a, cb, acc, 0, 0, 0);
            cb = nb_; nb_ = tb;
        }
        {
            s16x8 a = *(const s16x8*)(&tile[rt * 16 + l16][14 * 32 + q * 8]);
            acc = __builtin_amdgcn_mfma_f32_16x16x32_bf16(a, cb, acc, 0, 0, 0);
            a = *(const s16x8*)(&tile[rt * 16 + l16][15 * 32 + q * 8]);
            acc = __builtin_amdgcn_mfma_f32_16x16x32_bf16(a, nb_, acc, 0, 0, 0);
        }
        int col = ct * 16 + l16;
        if (col < 29) {
            float bias = bref[col];
#pragma unroll
            for (int r = 0; r < 4; r++) {
                int row = c0 + rt * 16 + q * 4 + r;
                outRef[(size_t)row * 29 + col] = acc[r] + bias;
            }
        }
    }
}

// ---- p_graph: per image, tiny adj contractions + broadcast sum -------------
__global__ __launch_bounds__(256) void pgraph2(
    const float* __restrict__ adjw, const float* __restrict__ Hp,
    const float* __restrict__ HoF, const float* __restrict__ Yh,
    const float* __restrict__ Zo, const float* __restrict__ bg,
    float* __restrict__ outG)
{
    int b = blockIdx.x, t = threadIdx.x;
    __shared__ float adjS[16][16];
    __shared__ float YhS[16][32];
    __shared__ float ZoS[15][32];
    __shared__ float PA[16][32];
    __shared__ float OA[16][32];
    adjS[t >> 4][t & 15] = adjw[b * 256 + t];
    for (int i = t; i < 512; i += 256)
        YhS[i >> 5][i & 31] = Yh[(size_t)(b * 16 + (i >> 5)) * 32 + (i & 31)];
    for (int i = t; i < 480; i += 256)
        ZoS[i >> 5][i & 31] = Zo[(size_t)(b * 15 + (i >> 5)) * 32 + (i & 31)];
    __syncthreads();
    for (int i = t; i < 512; i += 256) {
        int p = i >> 5, j = i & 31;
        float s = 0.f;
#pragma unroll
        for (int o = 0; o < 15; o++) s += adjS[p][o + 1] * ZoS[o][j];
        PA[p][j] = s;
        float s2 = 0.f;
#pragma unroll
        for (int pp = 0; pp < 16; pp++) s2 += adjS[pp][p] * YhS[pp][j];
        OA[p][j] = s2;
    }
    __syncthreads();
    int p = t >> 4, l = t & 15;
    const float* hp = Hp + (size_t)(b * 16 + p) * 32;
    const float* ho = HoF + (size_t)(b * 16 + l) * 32;
    size_t c = (size_t)b * 256 + t;
    for (int j = 0; j < 29; j++) {
        float v = hp[j] + ho[j] + bg[j] + PA[p][j];
        if (l >= 1) v += OA[l][j];
        outG[c * 29 + j] = v;
    }
}

extern "C" void kernel_launch(void* const* d_in, const int* in_sizes, int n_in,
                              void* d_out, int out_size, void* d_ws, size_t ws_size,
                              hipStream_t stream)
{
    const float* people  = (const float*)d_in[0];
    const float* objects = (const float*)d_in[1];
    const float* context = (const float*)d_in[2];
    const float* spatial = (const float*)d_in[3];
    const float* Wvis_w  = (const float*)d_in[4];
    const float* Wvis_b  = (const float*)d_in[5];
    const float* Wspat_w = (const float*)d_in[6];
    const float* Wspat_b = (const float*)d_in[7];
    const float* Wip_w   = (const float*)d_in[8];
    const float* Wip_b   = (const float*)d_in[9];
    const float* Wref_w  = (const float*)d_in[10];
    const float* Wref_b  = (const float*)d_in[11];
    const float* Watt_w  = (const float*)d_in[12];
    const float* Watt_b  = (const float*)d_in[13];
    const float* Woh_w   = (const float*)d_in[14];
    const float* Woh_b   = (const float*)d_in[15];
    const float* Who_w   = (const float*)d_in[16];
    const float* Who_b   = (const float*)d_in[17];
    const float* Wg_w    = (const float*)d_in[18];
    const float* Wg_b    = (const float*)d_in[19];

    char* ws = (char*)d_ws;
    u16* WspatT = (u16*)(ws + OFF_WSPATT);
    u16* WrefT  = (u16*)(ws + OFF_WREFT);
    u16* WattT  = (u16*)(ws + OFF_WATTT);
    u16* WgT    = (u16*)(ws + OFF_WGT);
    u16* Ppb    = (u16*)(ws + OFF_PP);
    u16* Pob    = (u16*)(ws + OFF_PO);
    u16* Pcb    = (u16*)(ws + OFF_PC);
    float* adjw = (float*)(ws + OFF_ADJ);
    float* Hp   = (float*)(ws + OFF_HP);
    float* HoF  = (float*)(ws + OFF_HOF);
    float* Yh   = (float*)(ws + OFF_YH);
    float* Zo   = (float*)(ws + OFF_ZO);
    u16* WvisT2 = (u16*)(ws + OFF_WVIST2);
    u16* WhoT2  = (u16*)(ws + OFF_WHOT2);
    u16* WohT2  = (u16*)(ws + OFF_WOHT2);
    u16* peoB   = (u16*)(ws + OFF_PEOB);
    u16* objB   = (u16*)(ws + OFF_OBJB);
    u16* ctxB   = (u16*)(ws + OFF_CTXB);
    u16* spatB  = (u16*)(ws + OFF_SPATB);

    float* outI   = (float*)d_out;        // i_ho   [16384]
    float* outRef = outI + 16384;         // p_ref  [16384,29]
    float* outAtt = outI + 491520;        // p_att  [16384,29]
    float* outG   = outI + 966656;        // p_graph[16384,29]

    hipMemsetAsync(ws + ZERO_OFF, 0, ZERO_LEN, stream);

    prep_all<<<1408, 256, 0, stream>>>(people, objects, context, spatial,
        Wvis_w, Who_w, Woh_w, Wspat_w, Wref_w, Watt_w, Wg_w,
        peoB, objB, ctxB, spatB, WvisT2, WhoT2, WohT2,
        WspatT, WrefT, WattT, WgT);

    fused_gemms<<<648, 256, 0, stream>>>(peoB, objB, ctxB, WvisT2,
        WhoT2, Who_b, WohT2, Woh_b, WgT,
        Ppb, Pob, Pcb, Yh, Zo, Hp, HoF);

    mega<<<512, 256, 0, stream>>>(spatB, WspatT, Wspat_b,
                                  Ppb, Pob, Pcb, Wvis_b,
                                  WrefT, Wref_b, WattT, Watt_b,
                                  Wip_w, Wip_b,
                                  outI, outRef, outAtt, adjw);

    pgraph2<<<64, 256, 0, stream>>>(adjw, Hp, HoF, Yh, Zo, Wg_b, outG);
}